// Round 9
// baseline (438.338 us; speedup 1.0000x reference)
//
#include <hip/hip_runtime.h>
#include <hip/hip_bf16.h>

#define OUTF 1024
#define NROWS 65536
#define NBR 4
#define XBROWS 66560     // rowlist capacity (256-aligned branch segments)
#define NWG 1040         // 260 M-tiles(256) * 4 N-tiles(256), %8==0

typedef __attribute__((ext_vector_type(8))) short short8;
typedef __attribute__((ext_vector_type(4))) float f32x4;

__device__ inline unsigned short f2bf(float f) {
    return __builtin_bit_cast(unsigned short, (__bf16)f);
}
__device__ inline void gload_lds16(const void* g, void* l) {
    __builtin_amdgcn_global_load_lds(
        (const __attribute__((address_space(1))) void*)g,
        (__attribute__((address_space(3))) void*)l, 16, 0, 0);
}
__device__ inline short8 pack8(float4 a, float4 b) {
    short8 o;
    o[0] = (short)f2bf(a.x); o[1] = (short)f2bf(a.y);
    o[2] = (short)f2bf(a.z); o[3] = (short)f2bf(a.w);
    o[4] = (short)f2bf(b.x); o[5] = (short)f2bf(b.y);
    o[6] = (short)f2bf(b.z); o[7] = (short)f2bf(b.w);
    return o;
}
// 256-aligned segment bases from counts (prefix kernel folded away)
__device__ inline void seg_bases(const int* __restrict__ ws_i, int* base) {
    int s = 0;
    #pragma unroll
    for (int b = 0; b < NBR; b++) { base[b] = s; s = (s + ws_i[b] + 255) & ~255; }
}

// ws int layout: [0..3] counts, [8..11] fill positions (bases computed locally)
__global__ void k_count(const int* __restrict__ feat, int* __restrict__ cnt) {
    __shared__ int lc[NBR];
    int tid = threadIdx.x;
    if (tid < NBR) lc[tid] = 0;
    __syncthreads();
    int r = blockIdx.x * 256 + tid;
    int b = 26 - __clz(feat[r]);  // 32->0, 64->1, 128->2, 256->3
    atomicAdd(&lc[b], 1);
    __syncthreads();
    if (tid < NBR && lc[tid]) atomicAdd(&cnt[tid], lc[tid]);
}

__global__ void k_fill(const int* __restrict__ feat, int* __restrict__ ws,
                       int* __restrict__ rowlist) {
    int base[NBR];
    seg_bases(ws, base);
    int tid = threadIdx.x;
    int lane = tid & 63;
    int r = blockIdx.x * 256 + tid;
    int b = 26 - __clz(feat[r]);
    #pragma unroll
    for (int bb = 0; bb < NBR; bb++) {
        unsigned long long mask = __ballot(b == bb);
        int leader = __ffsll((long long)mask) - 1;
        int cntw = __popcll(mask);
        int basepos = 0;
        if (lane == leader) basepos = atomicAdd(&ws[8 + bb], cntw);
        basepos = __shfl(basepos, leader < 0 ? 0 : leader);
        if (b == bb) {
            int prefix = __popcll(mask & ((1ull << lane) - 1ull));
            rowlist[base[bb] + basepos + prefix] = r;
        }
    }
}

// W fp32 -> bf16, pre-swizzled (verified rounds 5/6: zero read conflicts):
// wsw[br][n][kw*128 + cb] = bf16(W[br][n][kw*64 + ((cb ^ ((n&7)<<4)) >> 1)])
__global__ void k_convw(const float* __restrict__ w, unsigned short* __restrict__ wsw) {
    int idx = (int)blockIdx.x * 256 + (int)threadIdx.x;   // 16B chunks
    int branch = idx >> 17;
    int rem = idx & 131071;
    int n = rem >> 7;
    int cb = (rem & 127) << 4;
    int kw = cb >> 7;
    int wb_ = cb & 127;
    int src = kw * 64 + ((wb_ ^ ((n & 7) << 4)) >> 1);
    const float4* s = reinterpret_cast<const float4*>(
        w + ((size_t)branch << 20) + (size_t)n * OUTF + src);
    char* dst = reinterpret_cast<char*>(wsw) + ((size_t)branch << 21) + (size_t)n * 2048 + cb;
    *reinterpret_cast<short8*>(dst) = pack8(s[0], s[1]);
}

// 256x256x64 GEMM, 8 waves (2M x 4N), R6's verified fragment/LDS math.
// A: reg-staged direct from fp32 x (issue at iter top, cvt+swizzled ds_write
// after compute -> compute phase covers HBM latency). B: gload_lds from
// pre-swizzled wsw. Double-buffered A(2x32K)+B(2x32K) = 128 KiB.
__global__ __launch_bounds__(512, 2)
void k_gemm8(const float* __restrict__ x,
             const unsigned short* __restrict__ wsw,
             const float* __restrict__ bias,
             const int* __restrict__ ws_i,
             const int* __restrict__ rowlist,
             float* __restrict__ out) {
    extern __shared__ char lds[];   // A0 @0, A1 @32768, B0 @65536, B1 @98304

    // XCD-chunk swizzle, M-tile-major within chunk (A-panel L2 reuse, 4 N-tiles)
    const int d = (int)blockIdx.x;
    const int work = (d & 7) * (NWG >> 3) + (d >> 3);
    const int mtile = work >> 2;
    const int ntile = work & 3;

    int bases[NBR];
    seg_bases(ws_i, bases);
    int branch = -1, lt = 0, cnt = 0, rbase = 0;
    int t_ = mtile;
    #pragma unroll
    for (int b = 0; b < NBR; b++) {
        if (branch < 0) {
            int c = ws_i[b];
            int nt = (c + 255) >> 8;
            if (t_ < nt) { branch = b; lt = t_; cnt = c; rbase = bases[b]; }
            else t_ -= nt;
        }
    }
    if (branch < 0) return;

    const int tid = (int)threadIdx.x;
    const int lane = tid & 63;
    const int w8 = tid >> 6;
    const int wm = (w8 >> 2) * 128;   // 0/128
    const int wn = (w8 & 3) * 64;     // 0/64/128/192
    const int n0 = ntile * 256;
    const int row0 = rbase + lt * 256;

    // ---- A staging: thread covers row tid>>1 (0..255), half h = tid&1 (32 fp32)
    const int sarow = tid >> 1;
    const int h = tid & 1;
    int arl = rowlist[row0 + sarow];
    if ((unsigned)arl >= NROWS) arl = 0;     // pad-gap (0xAA poison) -> row 0
    const float* aSrc = x + (size_t)arl * OUTF + h * 32;
    const int arb = sarow * 128;
    int awoff[4];
    #pragma unroll
    for (int j = 0; j < 4; j++)
        awoff[j] = arb + (((h * 4 + j) << 4) ^ ((sarow & 7) << 4));

    // ---- B staging: 4 gloads; unit i rows i*64+(tid>>3), chunk tid&7 (swizzle in wsw)
    const char* gb[4];
    #pragma unroll
    for (int i = 0; i < 4; i++) {
        int rn_ = i * 64 + (tid >> 3);
        gb[i] = reinterpret_cast<const char*>(wsw) + ((size_t)branch << 21)
                + (size_t)(n0 + rn_) * 2048 + ((tid & 7) << 4);
    }
    const int ldsoffB = tid << 4;

    f32x4 acc[8][4];
    #pragma unroll
    for (int i = 0; i < 8; i++)
        #pragma unroll
        for (int j = 0; j < 4; j++) acc[i][j] = (f32x4){0.f, 0.f, 0.f, 0.f};

    const int swz = (lane & 7) << 4;
    const int kq = (lane >> 4) << 4;
    const int arowb = (wm + (lane & 15)) * 128;
    const int browb = (wn + (lane & 15)) * 128;

    // ---- prologue: stage tile 0 fully
    {
        #pragma unroll
        for (int i = 0; i < 4; i++)
            gload_lds16(gb[i], lds + 65536 + i * 8192 + ldsoffB);
        const float4* p = reinterpret_cast<const float4*>(aSrc);
        float4 r0 = p[0], r1 = p[1], r2 = p[2], r3 = p[3];
        float4 r4 = p[4], r5 = p[5], r6 = p[6], r7 = p[7];
        asm volatile("s_waitcnt vmcnt(0)" ::: "memory");
        *reinterpret_cast<short8*>(lds + awoff[0]) = pack8(r0, r1);
        *reinterpret_cast<short8*>(lds + awoff[1]) = pack8(r2, r3);
        *reinterpret_cast<short8*>(lds + awoff[2]) = pack8(r4, r5);
        *reinterpret_cast<short8*>(lds + awoff[3]) = pack8(r6, r7);
        __syncthreads();
    }

    for (int t = 0; t < 16; ++t) {
        char* Ac = lds + (t & 1) * 32768;
        char* Bc = lds + 65536 + (t & 1) * 32768;
        float4 rn[8];

        // issue next tile's loads (B -> LDS direct, A -> regs)
        if (t < 15) {
            char* Bn = lds + 65536 + ((t + 1) & 1) * 32768;
            #pragma unroll
            for (int i = 0; i < 4; i++)
                gload_lds16(gb[i] + (t + 1) * 128, Bn + i * 8192 + ldsoffB);
            const float4* p = reinterpret_cast<const float4*>(aSrc + (t + 1) * 64);
            #pragma unroll
            for (int j = 0; j < 8; j++) rn[j] = p[j];
        }
        __builtin_amdgcn_sched_barrier(0);   // pin issues above compute

        // compute tile t (R6-verified pattern; af in two halves of 4)
        #pragma unroll
        for (int ks = 0; ks < 2; ks++) {
            const int kb = (ks << 6) + kq;
            short8 bf_[4];
            #pragma unroll
            for (int j = 0; j < 4; j++)
                bf_[j] = *reinterpret_cast<const short8*>(Bc + browb + j * 2048 + (kb ^ swz));
            #pragma unroll
            for (int hh = 0; hh < 2; hh++) {
                short8 af[4];
                #pragma unroll
                for (int i = 0; i < 4; i++)
                    af[i] = *reinterpret_cast<const short8*>(
                        Ac + arowb + (hh * 4 + i) * 2048 + (kb ^ swz));
                __builtin_amdgcn_s_setprio(1);
                #pragma unroll
                for (int i = 0; i < 4; i++)
                    #pragma unroll
                    for (int j = 0; j < 4; j++)
                        acc[hh * 4 + i][j] = __builtin_amdgcn_mfma_f32_16x16x32_bf16(
                            af[i], bf_[j], acc[hh * 4 + i][j], 0, 0, 0);
                __builtin_amdgcn_s_setprio(0);
            }
        }

        // write A(t+1) after compute (loads had the whole compute phase to land)
        if (t < 15) {
            asm volatile("s_waitcnt vmcnt(0)" ::: "memory");
            char* An = lds + ((t + 1) & 1) * 32768;
            *reinterpret_cast<short8*>(An + awoff[0]) = pack8(rn[0], rn[1]);
            *reinterpret_cast<short8*>(An + awoff[1]) = pack8(rn[2], rn[3]);
            *reinterpret_cast<short8*>(An + awoff[2]) = pack8(rn[4], rn[5]);
            *reinterpret_cast<short8*>(An + awoff[3]) = pack8(rn[6], rn[7]);
        }
        __syncthreads();
    }

    // epilogue: + bias, scatter to original rows. C/D map: col=lane&15, row=(lane>>4)*4+reg
    const int ccol = lane & 15;
    const int crow = (lane >> 4) << 2;
    float bv[4];
    const float* bp = bias + branch * OUTF + n0 + wn;
    #pragma unroll
    for (int fn = 0; fn < 4; fn++) bv[fn] = bp[fn * 16 + ccol];
    #pragma unroll
    for (int fm = 0; fm < 8; fm++) {
        #pragma unroll
        for (int j = 0; j < 4; j++) {
            int gm = lt * 256 + wm + fm * 16 + crow + j;
            if (gm < cnt) {
                int orow = rowlist[rbase + gm];
                float* orp = out + (size_t)orow * OUTF + n0 + wn;
                #pragma unroll
                for (int fn = 0; fn < 4; fn++)
                    orp[fn * 16 + ccol] = acc[fm][fn][j] + bv[fn];
            }
        }
    }
}

// ---------------- fallback (direct, fp32 W) if ws is too small ----------------
__global__ __launch_bounds__(256, 3)
void k_gemm_fb(const float* __restrict__ x,
               const float* __restrict__ wf,
               const float* __restrict__ bias,
               const int* __restrict__ ws_i,
               const int* __restrict__ rowlist,
               float* __restrict__ out) {
    __shared__ unsigned short As[128][72];
    __shared__ unsigned short Bs[128][72];

    int bases[NBR];
    seg_bases(ws_i, bases);
    int t = (int)blockIdx.x;
    int branch = -1, ltile = 0, cnt = 0, rbase = 0;
    #pragma unroll
    for (int b = 0; b < NBR; b++) {
        if (branch < 0) {
            int c = ws_i[b];
            int nt = (c + 127) >> 7;
            if (t < nt) { branch = b; ltile = t; cnt = c; rbase = bases[b]; }
            else t -= nt;
        }
    }
    if (branch < 0) return;

    const int tid = threadIdx.x;
    const int lane = tid & 63;
    const int wid = tid >> 6;
    const int wm = (wid & 1) << 6;
    const int wn = (wid >> 1) << 6;
    const int n0 = (int)blockIdx.y * 128;

    const int srow = tid >> 1;
    const int scol = (tid & 1) << 5;

    const int gmrow = ltile * 128 + srow;
    int grl = (gmrow < cnt) ? rowlist[rbase + gmrow] : -1;
    if (grl >= NROWS) grl = -1;
    const float* xsrc = x + (size_t)(grl < 0 ? 0 : grl) * OUTF + scol;
    const float* wfsrc = wf + ((size_t)branch << 20) + (size_t)(n0 + srow) * OUTF + scol;

    f32x4 acc[4][4];
    #pragma unroll
    for (int i = 0; i < 4; i++)
        #pragma unroll
        for (int j = 0; j < 4; j++)
            acc[i][j] = (f32x4){0.f, 0.f, 0.f, 0.f};

    for (int k0 = 0; k0 < OUTF; k0 += 64) {
        {
            unsigned short* dst = &As[srow][scol];
            if (grl >= 0) {
                const float4* s4 = reinterpret_cast<const float4*>(xsrc + k0);
                #pragma unroll
                for (int i = 0; i < 8; i += 2)
                    *reinterpret_cast<short8*>(dst + i * 4) = pack8(s4[i], s4[i + 1]);
            } else {
                short8 z = (short8){0, 0, 0, 0, 0, 0, 0, 0};
                #pragma unroll
                for (int i = 0; i < 8; i += 2) *reinterpret_cast<short8*>(dst + i * 4) = z;
            }
        }
        {
            unsigned short* dst = &Bs[srow][scol];
            const float4* s4 = reinterpret_cast<const float4*>(wfsrc + k0);
            #pragma unroll
            for (int i = 0; i < 8; i += 2)
                *reinterpret_cast<short8*>(dst + i * 4) = pack8(s4[i], s4[i + 1]);
        }
        __syncthreads();
        #pragma unroll
        for (int kk = 0; kk < 64; kk += 32) {
            const int krd = kk + (lane >> 4) * 8;
            short8 af[4], bf_[4];
            #pragma unroll
            for (int i = 0; i < 4; i++)
                af[i] = *reinterpret_cast<const short8*>(&As[wm + i * 16 + (lane & 15)][krd]);
            #pragma unroll
            for (int i = 0; i < 4; i++)
                bf_[i] = *reinterpret_cast<const short8*>(&Bs[wn + i * 16 + (lane & 15)][krd]);
            #pragma unroll
            for (int i = 0; i < 4; i++)
                #pragma unroll
                for (int j = 0; j < 4; j++)
                    acc[i][j] = __builtin_amdgcn_mfma_f32_16x16x32_bf16(af[i], bf_[j], acc[i][j], 0, 0, 0);
        }
        __syncthreads();
    }

    const int ccol = lane & 15;
    const int crow = (lane >> 4) << 2;
    float bv[4];
    const float* bp = bias + branch * OUTF + n0 + wn;
    #pragma unroll
    for (int fn = 0; fn < 4; fn++) bv[fn] = bp[fn * 16 + ccol];
    #pragma unroll
    for (int fm = 0; fm < 4; fm++) {
        #pragma unroll
        for (int j = 0; j < 4; j++) {
            int gm = ltile * 128 + wm + fm * 16 + crow + j;
            if (gm < cnt) {
                int orow = rowlist[rbase + gm];
                float* orp = out + (size_t)orow * OUTF + n0 + wn;
                #pragma unroll
                for (int fn = 0; fn < 4; fn++)
                    orp[fn * 16 + ccol] = acc[fm][fn][j] + bv[fn];
            }
        }
    }
}

extern "C" void kernel_launch(void* const* d_in, const int* in_sizes, int n_in,
                              void* d_out, int out_size, void* d_ws, size_t ws_size,
                              hipStream_t stream) {
    const float* x = (const float*)d_in[0];
    const int* feat = (const int*)d_in[1];
    const float* w = (const float*)d_in[2];
    const float* bias = (const float*)d_in[3];
    float* out = (float*)d_out;

    char* ws = (char*)d_ws;
    int* ws_i = (int*)ws;
    int* rowlist = (int*)(ws + 256);                       // 66560*4 = 266 KB
    const size_t WSW_OFF = (size_t)512 << 10;              // 512 KB
    unsigned short* wsw = (unsigned short*)(ws + WSW_OFF); // 8 MB bf16 W (pre-swizzled)
    const size_t need = WSW_OFF + (size_t)NBR * OUTF * OUTF * 2;  // ~8.9 MB

    (void)hipMemsetAsync(ws_i, 0, 64, stream);
    k_count<<<NROWS / 256, 256, 0, stream>>>(feat, ws_i);
    k_fill<<<NROWS / 256, 256, 0, stream>>>(feat, ws_i, rowlist);

    if (ws_size >= need) {
        k_convw<<<2048, 256, 0, stream>>>(w, wsw);
        (void)hipFuncSetAttribute((const void*)k_gemm8,
                                  hipFuncAttributeMaxDynamicSharedMemorySize, 131072);
        k_gemm8<<<NWG, 512, 131072, stream>>>(x, wsw, bias, ws_i, rowlist, out);
    } else {
        dim3 grid(NROWS / 128 + NBR, OUTF / 128);
        k_gemm_fb<<<grid, 256, 0, stream>>>(x, w, bias, ws_i, rowlist, out);
    }
}

// Round 10
// 349.860 us; speedup vs baseline: 1.2529x; 1.2529x over previous
//
#include <hip/hip_runtime.h>
#include <hip/hip_bf16.h>

#define OUTF 1024
#define NROWS 65536
#define NBR 4
#define XBROWS 66560     // rowlist/xb capacity (256-aligned branch segments)
#define NWG 1040         // 260 M-tiles(256) * 4 N-tiles(256), %8==0

typedef __attribute__((ext_vector_type(8))) short short8;
typedef __attribute__((ext_vector_type(4))) float f32x4;

__device__ inline unsigned short f2bf(float f) {
    return __builtin_bit_cast(unsigned short, (__bf16)f);
}
__device__ inline void gload_lds16(const void* g, void* l) {
    __builtin_amdgcn_global_load_lds(
        (const __attribute__((address_space(1))) void*)g,
        (__attribute__((address_space(3))) void*)l, 16, 0, 0);
}
__device__ inline short8 pack8(float4 a, float4 b) {
    short8 o;
    o[0] = (short)f2bf(a.x); o[1] = (short)f2bf(a.y);
    o[2] = (short)f2bf(a.z); o[3] = (short)f2bf(a.w);
    o[4] = (short)f2bf(b.x); o[5] = (short)f2bf(b.y);
    o[6] = (short)f2bf(b.z); o[7] = (short)f2bf(b.w);
    return o;
}
__device__ inline void seg_bases(const int* __restrict__ ws_i, int* base) {
    int s = 0;
    #pragma unroll
    for (int b = 0; b < NBR; b++) { base[b] = s; s = (s + ws_i[b] + 255) & ~255; }
}

#define SBAR()  do { __builtin_amdgcn_sched_barrier(0); __builtin_amdgcn_s_barrier(); \
                     __builtin_amdgcn_sched_barrier(0); } while (0)

// ws int layout: [0..3] counts, [8..11] fill positions
__global__ void k_count(const int* __restrict__ feat, int* __restrict__ cnt) {
    __shared__ int lc[NBR];
    int tid = threadIdx.x;
    if (tid < NBR) lc[tid] = 0;
    __syncthreads();
    int r = blockIdx.x * 256 + tid;
    int b = 26 - __clz(feat[r]);  // 32->0, 64->1, 128->2, 256->3
    atomicAdd(&lc[b], 1);
    __syncthreads();
    if (tid < NBR && lc[tid]) atomicAdd(&cnt[tid], lc[tid]);
}

__global__ void k_fill(const int* __restrict__ feat, int* __restrict__ ws,
                       int* __restrict__ rowlist) {
    int base[NBR];
    seg_bases(ws, base);
    int tid = threadIdx.x;
    int lane = tid & 63;
    int r = blockIdx.x * 256 + tid;
    int b = 26 - __clz(feat[r]);
    #pragma unroll
    for (int bb = 0; bb < NBR; bb++) {
        unsigned long long mask = __ballot(b == bb);
        int leader = __ffsll((long long)mask) - 1;
        int cntw = __popcll(mask);
        int basepos = 0;
        if (lane == leader) basepos = atomicAdd(&ws[8 + bb], cntw);
        basepos = __shfl(basepos, leader < 0 ? 0 : leader);
        if (b == bb) {
            int prefix = __popcll(mask & ((1ull << lane) - 1ull));
            rowlist[base[bb] + basepos + prefix] = r;
        }
    }
}

// W fp32 -> bf16, plain linear
__global__ void k_convw(const float* __restrict__ w, unsigned short* __restrict__ wb) {
    int i = ((int)blockIdx.x * 256 + (int)threadIdx.x) * 8;
    const float4* s = reinterpret_cast<const float4*>(w + i);
    *reinterpret_cast<short8*>(wb + i) = pack8(s[0], s[1]);
}

// x fp32 -> bf16, gathered into branch-contiguous (256-aligned) order, linear
__global__ void k_convx(const float* __restrict__ x, const int* __restrict__ rowlist,
                        unsigned short* __restrict__ xb) {
    int g = (int)blockIdx.x * 512 + (int)threadIdx.x;   // 16B-out chunks
    int orow = g >> 7;
    int cb = (g & 127) << 4;
    int rl = rowlist[orow];
    if ((unsigned)rl >= NROWS) rl = 0;   // pad-gap poison -> row 0
    const float4* s = reinterpret_cast<const float4*>(x + (size_t)rl * OUTF + (cb >> 1));
    *reinterpret_cast<short8*>(reinterpret_cast<char*>(xb) + (size_t)orow * 2048 + cb) =
        pack8(s[0], s[1]);
}

// ===== m201-template 256x256x64 GEMM, 8 waves (2M x 4N), 4 phases/K-tile =====
// Staging unit = K-half-tile: 256 rows x 32 K bf16 = 16 KB = 2 gload_lds/wave.
// Regions/K-tile: {A-k0, A-k1, B-k0, B-k1}; dbuf x 4 = 8 x 16 KB = 128 KiB.
// Phases (group t, buf rb=(t&1)<<2): p1=Mlo.k0 (read A-k0 lo + B-k0, 16 MFMA),
// p2=Mhi.k0 (A-k0 hi, B regs reused), p3=Mlo.k1, p4=Mhi.k1  -> 8/4/8/4 ds_reads.
// Stage map (1 unit/phase): p1: A-k1(t+1); p2: B-k0(t+2); p3: A-k0(t+2); p4: B-k1(t+2).
//  write-after-read: each target region's last read completes before the issuing
//  phase starts (lgkm-drained by reader's MFMA + phase barrier).
//  land-before-read: vmcnt(6) at p4 leaves exactly the 3 newest units (tile t+2,
//  first read >= 1 vmcnt later) in flight; everything older is landed. Queue
//  never drains until t==14. Prologue: tile0 x4 + tile1 {B-k0,A-k0,B-k1}, vmcnt(6).
// Bank conflicts: row stride 64B -> chunk XOR g(r)=(r>>1)&3 applied on per-lane
// GLOBAL source (LDS dest linear); fragment reads land 2-way aliased = free.
__global__ __launch_bounds__(512, 2)
void k_gemm9(const unsigned short* __restrict__ xb,
             const unsigned short* __restrict__ wb,
             const float* __restrict__ bias,
             const int* __restrict__ ws_i,
             const int* __restrict__ rowlist,
             float* __restrict__ out) {
    extern __shared__ char lds[];

    // XCD-chunk swizzle, M-tile-major within chunk
    const int d = (int)blockIdx.x;
    const int work = (d & 7) * (NWG >> 3) + (d >> 3);
    const int mtile = work >> 2;
    const int ntile = work & 3;

    int bases[NBR];
    seg_bases(ws_i, bases);
    int branch = -1, lt = 0, cnt = 0, rbase = 0;
    int t_ = mtile;
    #pragma unroll
    for (int b = 0; b < NBR; b++) {
        if (branch < 0) {
            int c = ws_i[b];
            int nt = (c + 255) >> 8;
            if (t_ < nt) { branch = b; lt = t_; cnt = c; rbase = bases[b]; }
            else t_ -= nt;
        }
    }
    if (branch < 0) return;

    const int tid = (int)threadIdx.x;
    const int lane = tid & 63;
    const int w8 = tid >> 6;
    const int wm = (w8 >> 2) * 128;   // 0/128
    const int wn = (w8 & 3) * 64;     // 0/64/128/192
    const int n0 = ntile * 256;
    const int row0 = rbase + lt * 256;

    // staging sources: thread covers dest rows tid>>2 and (tid>>2)+128, chunk tid&3.
    // source chunk = destchunk ^ g(row), g(row) = (row>>1)&3 = (tid>>3)&3.
    const int schunk = ((tid & 3) ^ ((tid >> 3) & 3)) << 4;
    const char* aS = reinterpret_cast<const char*>(xb)
                     + (size_t)(row0 + (tid >> 2)) * 2048 + schunk;
    const char* bS = reinterpret_cast<const char*>(wb) + ((size_t)branch << 21)
                     + (size_t)(n0 + (tid >> 2)) * 2048 + schunk;
    const int dst16 = tid << 4;

    // unit stage: typ 0=A-k0, 1=A-k1, 2=B-k0, 3=B-k1; region = (tile&1)<<2 | typ
    auto STAGE = [&](int tile, int typ) {
        const char* s = (typ >= 2 ? bS : aS) + tile * 128 + (typ & 1) * 64;
        char* dd = lds + ((((tile & 1) << 2) | typ) << 14) + dst16;
        gload_lds16(s, dd);
        gload_lds16(s + 128 * 2048, dd + 8192);
    };

    f32x4 acc[8][4];
    #pragma unroll
    for (int i = 0; i < 8; i++)
        #pragma unroll
        for (int j = 0; j < 4; j++) acc[i][j] = (f32x4){0.f, 0.f, 0.f, 0.f};

    const int lr = lane & 15;
    const int axor = (((lane >> 4) ^ ((lr >> 1) & 3)) << 4);  // q ^ g(r), per-lane const
    const int arow = (wm + lr) * 64 + axor;   // + fi*1024 (+64*64 for Mhi)
    const int brow = (wn + lr) * 64 + axor;

    // ---- prologue: tile0 all 4 units + tile1 {B-k0, A-k0, B-k1}; vmcnt(6)
    STAGE(0, 2); STAGE(0, 0); STAGE(0, 3); STAGE(0, 1);
    STAGE(1, 2); STAGE(1, 0); STAGE(1, 3);
    asm volatile("s_waitcnt vmcnt(6)" ::: "memory");
    SBAR();

    short8 af[4], bf_[4];

    #pragma unroll 2
    for (int t = 0; t < 16; ++t) {
        const int rb = (t & 1) << 2;
        const char* A0 = lds + ((rb | 0) << 14);
        const char* A1 = lds + ((rb | 1) << 14);
        const char* B0 = lds + ((rb | 2) << 14);
        const char* B1 = lds + ((rb | 3) << 14);

        // ---- p1: Mlo x k0
        if (t < 15) STAGE(t + 1, 1);
        #pragma unroll
        for (int i = 0; i < 4; i++)
            af[i] = *reinterpret_cast<const short8*>(A0 + arow + i * 1024);
        #pragma unroll
        for (int j = 0; j < 4; j++)
            bf_[j] = *reinterpret_cast<const short8*>(B0 + brow + j * 1024);
        SBAR();
        __builtin_amdgcn_s_setprio(1);
        #pragma unroll
        for (int i = 0; i < 4; i++)
            #pragma unroll
            for (int j = 0; j < 4; j++)
                acc[i][j] = __builtin_amdgcn_mfma_f32_16x16x32_bf16(af[i], bf_[j], acc[i][j], 0, 0, 0);
        __builtin_amdgcn_s_setprio(0);
        SBAR();

        // ---- p2: Mhi x k0 (B k0 regs reused)
        if (t < 14) STAGE(t + 2, 2);
        #pragma unroll
        for (int i = 0; i < 4; i++)
            af[i] = *reinterpret_cast<const short8*>(A0 + arow + 4096 + i * 1024);
        SBAR();
        __builtin_amdgcn_s_setprio(1);
        #pragma unroll
        for (int i = 0; i < 4; i++)
            #pragma unroll
            for (int j = 0; j < 4; j++)
                acc[4 + i][j] = __builtin_amdgcn_mfma_f32_16x16x32_bf16(af[i], bf_[j], acc[4 + i][j], 0, 0, 0);
        __builtin_amdgcn_s_setprio(0);
        SBAR();

        // ---- p3: Mlo x k1
        if (t < 14) STAGE(t + 2, 0);
        #pragma unroll
        for (int i = 0; i < 4; i++)
            af[i] = *reinterpret_cast<const short8*>(A1 + arow + i * 1024);
        #pragma unroll
        for (int j = 0; j < 4; j++)
            bf_[j] = *reinterpret_cast<const short8*>(B1 + brow + j * 1024);
        SBAR();
        __builtin_amdgcn_s_setprio(1);
        #pragma unroll
        for (int i = 0; i < 4; i++)
            #pragma unroll
            for (int j = 0; j < 4; j++)
                acc[i][j] = __builtin_amdgcn_mfma_f32_16x16x32_bf16(af[i], bf_[j], acc[i][j], 0, 0, 0);
        __builtin_amdgcn_s_setprio(0);
        SBAR();

        // ---- p4: Mhi x k1
        if (t < 14) STAGE(t + 2, 3);
        #pragma unroll
        for (int i = 0; i < 4; i++)
            af[i] = *reinterpret_cast<const short8*>(A1 + arow + 4096 + i * 1024);
        SBAR();
        __builtin_amdgcn_s_setprio(1);
        #pragma unroll
        for (int i = 0; i < 4; i++)
            #pragma unroll
            for (int j = 0; j < 4; j++)
                acc[4 + i][j] = __builtin_amdgcn_mfma_f32_16x16x32_bf16(af[i], bf_[j], acc[4 + i][j], 0, 0, 0);
        __builtin_amdgcn_s_setprio(0);
        __builtin_amdgcn_sched_barrier(0);
        if (t < 14)      { asm volatile("s_waitcnt vmcnt(6)" ::: "memory"); }
        else if (t == 14){ asm volatile("s_waitcnt vmcnt(0)" ::: "memory"); }
        __builtin_amdgcn_sched_barrier(0);
        __builtin_amdgcn_s_barrier();
        __builtin_amdgcn_sched_barrier(0);
    }

    // epilogue: + bias, scatter to original rows. C/D map: col=lane&15, row=(lane>>4)*4+reg
    const int ccol = lane & 15;
    const int crow = (lane >> 4) << 2;
    float bv[4];
    const float* bp = bias + branch * OUTF + n0 + wn;
    #pragma unroll
    for (int fn = 0; fn < 4; fn++) bv[fn] = bp[fn * 16 + ccol];
    #pragma unroll
    for (int fm = 0; fm < 8; fm++) {
        #pragma unroll
        for (int j = 0; j < 4; j++) {
            int gm = lt * 256 + wm + fm * 16 + crow + j;
            if (gm < cnt) {
                int orow = rowlist[rbase + gm];
                float* orp = out + (size_t)orow * OUTF + n0 + wn;
                #pragma unroll
                for (int fn = 0; fn < 4; fn++)
                    orp[fn * 16 + ccol] = acc[fm][fn][j] + bv[fn];
            }
        }
    }
}

// ---------------- fallback (direct, fp32 W) if ws is too small ----------------
__global__ __launch_bounds__(256, 3)
void k_gemm_fb(const float* __restrict__ x,
               const float* __restrict__ wf,
               const float* __restrict__ bias,
               const int* __restrict__ ws_i,
               const int* __restrict__ rowlist,
               float* __restrict__ out) {
    __shared__ unsigned short As[128][72];
    __shared__ unsigned short Bs[128][72];

    int bases[NBR];
    seg_bases(ws_i, bases);
    int t = (int)blockIdx.x;
    int branch = -1, ltile = 0, cnt = 0, rbase = 0;
    #pragma unroll
    for (int b = 0; b < NBR; b++) {
        if (branch < 0) {
            int c = ws_i[b];
            int nt = (c + 255) >> 8;
            nt <<= 1;
            if (t < nt) { branch = b; ltile = t; cnt = c; rbase = bases[b]; }
            else t -= nt;
        }
    }
    if (branch < 0) return;

    const int tid = threadIdx.x;
    const int lane = tid & 63;
    const int wid = tid >> 6;
    const int wm = (wid & 1) << 6;
    const int wn = (wid >> 1) << 6;
    const int n0 = (int)blockIdx.y * 128;

    const int srow = tid >> 1;
    const int scol = (tid & 1) << 5;

    const int gmrow = ltile * 128 + srow;
    int grl = (gmrow < cnt) ? rowlist[rbase + gmrow] : -1;
    if (grl >= NROWS) grl = -1;
    const float* xsrc = x + (size_t)(grl < 0 ? 0 : grl) * OUTF + scol;
    const float* wfsrc = wf + ((size_t)branch << 20) + (size_t)(n0 + srow) * OUTF + scol;

    f32x4 acc[4][4];
    #pragma unroll
    for (int i = 0; i < 4; i++)
        #pragma unroll
        for (int j = 0; j < 4; j++)
            acc[i][j] = (f32x4){0.f, 0.f, 0.f, 0.f};

    for (int k0 = 0; k0 < OUTF; k0 += 64) {
        {
            unsigned short* dst = &As[srow][scol];
            if (grl >= 0) {
                const float4* s4 = reinterpret_cast<const float4*>(xsrc + k0);
                #pragma unroll
                for (int i = 0; i < 8; i += 2)
                    *reinterpret_cast<short8*>(dst + i * 4) = pack8(s4[i], s4[i + 1]);
            } else {
                short8 z = (short8){0, 0, 0, 0, 0, 0, 0, 0};
                #pragma unroll
                for (int i = 0; i < 8; i += 2) *reinterpret_cast<short8*>(dst + i * 4) = z;
            }
        }
        {
            unsigned short* dst = &Bs[srow][scol];
            const float4* s4 = reinterpret_cast<const float4*>(wfsrc + k0);
            #pragma unroll
            for (int i = 0; i < 8; i += 2)
                *reinterpret_cast<short8*>(dst + i * 4) = pack8(s4[i], s4[i + 1]);
        }
        __syncthreads();
        #pragma unroll
        for (int kk = 0; kk < 64; kk += 32) {
            const int krd = kk + (lane >> 4) * 8;
            short8 af[4], bf_[4];
            #pragma unroll
            for (int i = 0; i < 4; i++)
                af[i] = *reinterpret_cast<const short8*>(&As[wm + i * 16 + (lane & 15)][krd]);
            #pragma unroll
            for (int i = 0; i < 4; i++)
                bf_[i] = *reinterpret_cast<const short8*>(&Bs[wn + i * 16 + (lane & 15)][krd]);
            #pragma unroll
            for (int i = 0; i < 4; i++)
                #pragma unroll
                for (int j = 0; j < 4; j++)
                    acc[i][j] = __builtin_amdgcn_mfma_f32_16x16x32_bf16(af[i], bf_[j], acc[i][j], 0, 0, 0);
        }
        __syncthreads();
    }

    const int ccol = lane & 15;
    const int crow = (lane >> 4) << 2;
    float bv[4];
    const float* bp = bias + branch * OUTF + n0 + wn;
    #pragma unroll
    for (int fn = 0; fn < 4; fn++) bv[fn] = bp[fn * 16 + ccol];
    #pragma unroll
    for (int fm = 0; fm < 4; fm++) {
        #pragma unroll
        for (int j = 0; j < 4; j++) {
            int gm = ltile * 128 + wm + fm * 16 + crow + j;
            if (gm < cnt) {
                int orow = rowlist[rbase + gm];
                float* orp = out + (size_t)orow * OUTF + n0 + wn;
                #pragma unroll
                for (int fn = 0; fn < 4; fn++)
                    orp[fn * 16 + ccol] = acc[fm][fn][j] + bv[fn];
            }
        }
    }
}

extern "C" void kernel_launch(void* const* d_in, const int* in_sizes, int n_in,
                              void* d_out, int out_size, void* d_ws, size_t ws_size,
                              hipStream_t stream) {
    const float* x = (const float*)d_in[0];
    const int* feat = (const int*)d_in[1];
    const float* w = (const float*)d_in[2];
    const float* bias = (const float*)d_in[3];
    float* out = (float*)d_out;

    char* ws = (char*)d_ws;
    int* ws_i = (int*)ws;
    int* rowlist = (int*)(ws + 256);                       // 266 KB
    const size_t WB_OFF = (size_t)512 << 10;               // 512 KB
    const size_t XB_OFF = (size_t)9 << 20;                 // 9 MB
    unsigned short* wb = (unsigned short*)(ws + WB_OFF);   // 8 MB bf16 W
    unsigned short* xb = (unsigned short*)(ws + XB_OFF);   // 136.3 MB bf16 x (permuted)
    const size_t need_full = XB_OFF + (size_t)XBROWS * 2048;

    (void)hipMemsetAsync(ws_i, 0, 64, stream);
    k_count<<<NROWS / 256, 256, 0, stream>>>(feat, ws_i);
    k_fill<<<NROWS / 256, 256, 0, stream>>>(feat, ws_i, rowlist);

    if (ws_size >= need_full) {
        k_convw<<<(NBR * OUTF * OUTF) / (256 * 8), 256, 0, stream>>>(w, wb);
        k_convx<<<(XBROWS * 128) / 512, 512, 0, stream>>>(x, rowlist, xb);
        (void)hipFuncSetAttribute((const void*)k_gemm9,
                                  hipFuncAttributeMaxDynamicSharedMemorySize, 131072);
        k_gemm9<<<NWG, 512, 131072, stream>>>(xb, wb, bias, ws_i, rowlist, out);
    } else {
        dim3 grid(NROWS / 128 + 2 * NBR, OUTF / 128);
        k_gemm_fb<<<grid, 256, 0, stream>>>(x, w, bias, ws_i, rowlist, out);
    }
}

// Round 11
// 333.093 us; speedup vs baseline: 1.3160x; 1.0503x over previous
//
#include <hip/hip_runtime.h>
#include <hip/hip_bf16.h>

#define OUTF 1024
#define NROWS 65536
#define NBR 4
#define XBROWS 66560     // rowlist capacity (256-aligned branch segments)
#define NWG 2064         // 516 M-tiles(128) * 4 N-tiles(256), %8==0

typedef __attribute__((ext_vector_type(8))) short short8;
typedef __attribute__((ext_vector_type(4))) float f32x4;

__device__ inline unsigned short f2bf(float f) {
    return __builtin_bit_cast(unsigned short, (__bf16)f);
}
__device__ inline void gload_lds16(const void* g, void* l) {
    __builtin_amdgcn_global_load_lds(
        (const __attribute__((address_space(1))) void*)g,
        (__attribute__((address_space(3))) void*)l, 16, 0, 0);
}
__device__ inline short8 pack8(float4 a, float4 b) {
    short8 o;
    o[0] = (short)f2bf(a.x); o[1] = (short)f2bf(a.y);
    o[2] = (short)f2bf(a.z); o[3] = (short)f2bf(a.w);
    o[4] = (short)f2bf(b.x); o[5] = (short)f2bf(b.y);
    o[6] = (short)f2bf(b.z); o[7] = (short)f2bf(b.w);
    return o;
}
__device__ inline short8 pack8v(f32x4 a, f32x4 b) {
    short8 o;
    o[0] = (short)f2bf(a[0]); o[1] = (short)f2bf(a[1]);
    o[2] = (short)f2bf(a[2]); o[3] = (short)f2bf(a[3]);
    o[4] = (short)f2bf(b[0]); o[5] = (short)f2bf(b[1]);
    o[6] = (short)f2bf(b[2]); o[7] = (short)f2bf(b[3]);
    return o;
}
__device__ inline void seg_bases(const int* __restrict__ ws_i, int* base) {
    int s = 0;
    #pragma unroll
    for (int b = 0; b < NBR; b++) { base[b] = s; s = (s + ws_i[b] + 255) & ~255; }
}

// ws int layout: [0..3] counts, [8..11] fill positions
__global__ void k_count(const int* __restrict__ feat, int* __restrict__ cnt) {
    __shared__ int lc[NBR];
    int tid = threadIdx.x;
    if (tid < NBR) lc[tid] = 0;
    __syncthreads();
    int r = blockIdx.x * 256 + tid;
    int b = 26 - __clz(feat[r]);  // 32->0, 64->1, 128->2, 256->3
    atomicAdd(&lc[b], 1);
    __syncthreads();
    if (tid < NBR && lc[tid]) atomicAdd(&cnt[tid], lc[tid]);
}

__global__ void k_fill(const int* __restrict__ feat, int* __restrict__ ws,
                       int* __restrict__ rowlist) {
    int base[NBR];
    seg_bases(ws, base);
    int tid = threadIdx.x;
    int lane = tid & 63;
    int r = blockIdx.x * 256 + tid;
    int b = 26 - __clz(feat[r]);
    #pragma unroll
    for (int bb = 0; bb < NBR; bb++) {
        unsigned long long mask = __ballot(b == bb);
        int leader = __ffsll((long long)mask) - 1;
        int cntw = __popcll(mask);
        int basepos = 0;
        if (lane == leader) basepos = atomicAdd(&ws[8 + bb], cntw);
        basepos = __shfl(basepos, leader < 0 ? 0 : leader);
        if (b == bb) {
            int prefix = __popcll(mask & ((1ull << lane) - 1ull));
            rowlist[base[bb] + basepos + prefix] = r;
        }
    }
}

// W fp32 -> bf16, pre-swizzled (R5/R6-verified zero-conflict B path):
// wsw[br][n][kw*128 + cb] = bf16(W[br][n][kw*64 + ((cb ^ ((n&7)<<4)) >> 1)])
__global__ void k_convw(const float* __restrict__ w, unsigned short* __restrict__ wsw) {
    int idx = (int)blockIdx.x * 256 + (int)threadIdx.x;   // 16B chunks
    int branch = idx >> 17;
    int rem = idx & 131071;
    int n = rem >> 7;
    int cb = (rem & 127) << 4;
    int kw = cb >> 7;
    int wb_ = cb & 127;
    int src = kw * 64 + ((wb_ ^ ((n & 7) << 4)) >> 1);
    const float4* s = reinterpret_cast<const float4*>(
        w + ((size_t)branch << 20) + (size_t)n * OUTF + src);
    char* dst = reinterpret_cast<char*>(wsw) + ((size_t)branch << 21) + (size_t)n * 2048 + cb;
    *reinterpret_cast<short8*>(dst) = pack8(s[0], s[1]);
}

// ===== 128x256x64 GEMM, 8 waves (2M x 4N, 64x64 each), R6's measured-best =====
// schedule verbatim: A 3-deep (3x32K) + B 2-deep (2x32K) = 160 KiB; per iter
// issue B(t+1) then A(t+2); compute t; vmcnt(4) keeps A(t+2) in flight (~2 iters).
// A: gathered DIRECTLY from fp32 x via gload_lds (per-lane src addr; rowlist
// permutation + 32B-chunk XOR src-swizzle). fp32->bf16 in the fragment read.
//   A LDS: rows 0..127, 256 B/row, chunk32 c stores global chunk32 c^(row&7).
//   Fragment read: logical (ks*128+q*32+h*16) -> stored offset XOR (row&7)<<5.
//   Bank math: 64 lanes -> 32 unique 16B addrs (lr/lr+8 broadcast); bank-group
//   = q^(lr&3) uniform over 4 groups, 4 accesses/bank = minimum. Conflict-free.
// B: bf16 from pre-swizzled wsw (R6-verified zero-conflict).
__global__ __launch_bounds__(512, 1)
void k_gemm10(const float* __restrict__ x,
              const unsigned short* __restrict__ wsw,
              const float* __restrict__ bias,
              const int* __restrict__ ws_i,
              const int* __restrict__ rowlist,
              float* __restrict__ out) {
    extern __shared__ char lds[];   // A: 0,32768,65536 ; B: 98304,131072

    // XCD-chunk swizzle, M-tile-major within chunk (A-panel L2 reuse, 4 N-tiles)
    const int d = (int)blockIdx.x;
    const int work = (d & 7) * (NWG >> 3) + (d >> 3);
    const int mtile = work >> 2;
    const int ntile = work & 3;

    int bases[NBR];
    seg_bases(ws_i, bases);
    int branch = -1, lt = 0, cnt = 0, rbase = 0;
    int t_ = mtile;
    #pragma unroll
    for (int b = 0; b < NBR; b++) {
        if (branch < 0) {
            int c = ws_i[b];
            int nt = (c + 127) >> 7;   // 128-row tiles; ceil(c/128)*128 <= 256-aligned seg
            if (t_ < nt) { branch = b; lt = t_; cnt = c; rbase = bases[b]; }
            else t_ -= nt;
        }
    }
    if (branch < 0) return;

    const int tid = (int)threadIdx.x;
    const int lane = tid & 63;
    const int w8 = tid >> 6;
    const int wm = (w8 >> 2) * 64;    // 0/64
    const int wn = (w8 & 3) * 64;     // 0/64/128/192
    const int n0 = ntile * 256;
    const int row0 = rbase + lt * 128;

    // ---- A staging: unit i covers dest rows i*32+(tid>>4), 16B chunk tid&15.
    // src chunk32 = (c16>>1) ^ (row&7); row&7 = (tid>>4)&7 for all units.
    const char* aP[4];
    {
        const int c16 = tid & 15;
        const int r7 = (tid >> 4) & 7;
        const int asrc = ((((c16 >> 1) ^ r7) << 5) | ((c16 & 1) << 4));
        #pragma unroll
        for (int i = 0; i < 4; i++) {
            int idx = row0 + i * 32 + (tid >> 4);
            int rl = rowlist[idx < XBROWS ? idx : 0];
            if ((unsigned)rl >= NROWS) rl = 0;   // pad-gap poison -> row 0
            aP[i] = reinterpret_cast<const char*>(x) + ((size_t)rl << 12) + asrc;
        }
    }
    // ---- B staging (R6 exact): unit i rows i*64+(tid>>3), chunk tid&7
    const char* gb[4];
    #pragma unroll
    for (int i = 0; i < 4; i++) {
        int rn_ = i * 64 + (tid >> 3);
        gb[i] = reinterpret_cast<const char*>(wsw) + ((size_t)branch << 21)
                + (size_t)(n0 + rn_) * 2048 + ((tid & 7) << 4);
    }
    const int dst16 = tid << 4;

    f32x4 acc[4][4];
    #pragma unroll
    for (int i = 0; i < 4; i++)
        #pragma unroll
        for (int j = 0; j < 4; j++) acc[i][j] = (f32x4){0.f, 0.f, 0.f, 0.f};

    const int lr = lane & 15;
    const int q = lane >> 4;
    const int swz = (lane & 7) << 4;                 // B read swizzle (R6)
    const int arowb = (wm + lr) * 256;               // A row base (256 B/row)
    const int browb = (wn + lr) * 128;               // B row base (128 B/row)

    // prologue: A(0), A(1), B(0)
    #pragma unroll
    for (int i = 0; i < 4; i++) gload_lds16(aP[i], lds + i * 8192 + dst16);
    #pragma unroll
    for (int i = 0; i < 4; i++) gload_lds16(aP[i] + 256, lds + 32768 + i * 8192 + dst16);
    #pragma unroll
    for (int i = 0; i < 4; i++) gload_lds16(gb[i], lds + 98304 + i * 8192 + dst16);
    asm volatile("s_waitcnt vmcnt(0)" ::: "memory");
    __builtin_amdgcn_sched_barrier(0);
    __builtin_amdgcn_s_barrier();
    __builtin_amdgcn_sched_barrier(0);

    int ia = 0;  // t % 3
    for (int t = 0; t < 16; ++t) {
        char* Ac = lds + ia * 32768;
        char* Bc = lds + 98304 + (t & 1) * 32768;

        if (t < 15) {   // B(t+1) -> other B buf
            char* Bn = lds + 98304 + ((t + 1) & 1) * 32768;
            #pragma unroll
            for (int i = 0; i < 4; i++)
                gload_lds16(gb[i] + (t + 1) * 128, Bn + i * 8192 + dst16);
        }
        if (t < 14) {   // A(t+2) -> bufA[(t+2)%3]
            int ia2 = ia + 2; if (ia2 >= 3) ia2 -= 3;
            char* An = lds + ia2 * 32768;
            #pragma unroll
            for (int i = 0; i < 4; i++)
                gload_lds16(aP[i] + (t + 2) * 256, An + i * 8192 + dst16);
        }
        __builtin_amdgcn_sched_barrier(0);

        __builtin_amdgcn_s_setprio(1);
        #pragma unroll
        for (int ks = 0; ks < 2; ks++) {
            short8 af[4], bf_[4];
            #pragma unroll
            for (int i = 0; i < 4; i++) {
                const int aoff = (((ks * 4 + q) ^ (lr & 7)) << 5);
                const f32x4 v0 = *reinterpret_cast<const f32x4*>(Ac + arowb + i * 4096 + aoff);
                const f32x4 v1 = *reinterpret_cast<const f32x4*>(Ac + arowb + i * 4096 + aoff + 16);
                af[i] = pack8v(v0, v1);
            }
            const int kb = (ks << 6) + (q << 4);
            #pragma unroll
            for (int j = 0; j < 4; j++)
                bf_[j] = *reinterpret_cast<const short8*>(Bc + browb + j * 2048 + (kb ^ swz));
            #pragma unroll
            for (int i = 0; i < 4; i++)
                #pragma unroll
                for (int j = 0; j < 4; j++)
                    acc[i][j] = __builtin_amdgcn_mfma_f32_16x16x32_bf16(af[i], bf_[j], acc[i][j], 0, 0, 0);
        }
        __builtin_amdgcn_s_setprio(0);

        // drain everything except A(t+2)'s 4 newest loads (R6-verified)
        if (t < 14) { asm volatile("s_waitcnt vmcnt(4)" ::: "memory"); }
        else        { asm volatile("s_waitcnt vmcnt(0)" ::: "memory"); }
        __builtin_amdgcn_sched_barrier(0);
        __builtin_amdgcn_s_barrier();
        __builtin_amdgcn_sched_barrier(0);

        ia = (ia + 1 == 3) ? 0 : ia + 1;
    }

    // epilogue: + bias, scatter to original rows. C/D map: col=lane&15, row=(lane>>4)*4+reg
    const int ccol = lane & 15;
    const int crow = (lane >> 4) << 2;
    float bv[4];
    const float* bp = bias + branch * OUTF + n0 + wn;
    #pragma unroll
    for (int fn = 0; fn < 4; fn++) bv[fn] = bp[fn * 16 + ccol];
    #pragma unroll
    for (int fm = 0; fm < 4; fm++) {
        #pragma unroll
        for (int j = 0; j < 4; j++) {
            int gm = lt * 128 + wm + fm * 16 + crow + j;
            if (gm < cnt) {
                int orow = rowlist[rbase + gm];
                float* orp = out + (size_t)orow * OUTF + n0 + wn;
                #pragma unroll
                for (int fn = 0; fn < 4; fn++)
                    orp[fn * 16 + ccol] = acc[fm][fn][j] + bv[fn];
            }
        }
    }
}

// ---------------- fallback (direct, fp32 W) if ws is too small ----------------
__global__ __launch_bounds__(256, 3)
void k_gemm_fb(const float* __restrict__ x,
               const float* __restrict__ wf,
               const float* __restrict__ bias,
               const int* __restrict__ ws_i,
               const int* __restrict__ rowlist,
               float* __restrict__ out) {
    __shared__ unsigned short As[128][72];
    __shared__ unsigned short Bs[128][72];

    int bases[NBR];
    seg_bases(ws_i, bases);
    int t = (int)blockIdx.x;
    int branch = -1, ltile = 0, cnt = 0, rbase = 0;
    #pragma unroll
    for (int b = 0; b < NBR; b++) {
        if (branch < 0) {
            int c = ws_i[b];
            int nt = (c + 127) >> 7;
            if (t < nt) { branch = b; ltile = t; cnt = c; rbase = bases[b]; }
            else t -= nt;
        }
    }
    if (branch < 0) return;

    const int tid = threadIdx.x;
    const int lane = tid & 63;
    const int wid = tid >> 6;
    const int wm = (wid & 1) << 6;
    const int wn = (wid >> 1) << 6;
    const int n0 = (int)blockIdx.y * 128;

    const int srow = tid >> 1;
    const int scol = (tid & 1) << 5;

    const int gmrow = ltile * 128 + srow;
    int grl = (gmrow < cnt) ? rowlist[rbase + gmrow] : -1;
    if (grl >= NROWS) grl = -1;
    const float* xsrc = x + (size_t)(grl < 0 ? 0 : grl) * OUTF + scol;
    const float* wfsrc = wf + ((size_t)branch << 20) + (size_t)(n0 + srow) * OUTF + scol;

    f32x4 acc[4][4];
    #pragma unroll
    for (int i = 0; i < 4; i++)
        #pragma unroll
        for (int j = 0; j < 4; j++)
            acc[i][j] = (f32x4){0.f, 0.f, 0.f, 0.f};

    for (int k0 = 0; k0 < OUTF; k0 += 64) {
        {
            unsigned short* dst = &As[srow][scol];
            if (grl >= 0) {
                const float4* s4 = reinterpret_cast<const float4*>(xsrc + k0);
                #pragma unroll
                for (int i = 0; i < 8; i += 2)
                    *reinterpret_cast<short8*>(dst + i * 4) = pack8(s4[i], s4[i + 1]);
            } else {
                short8 z = (short8){0, 0, 0, 0, 0, 0, 0, 0};
                #pragma unroll
                for (int i = 0; i < 8; i += 2) *reinterpret_cast<short8*>(dst + i * 4) = z;
            }
        }
        {
            unsigned short* dst = &Bs[srow][scol];
            const float4* s4 = reinterpret_cast<const float4*>(wfsrc + k0);
            #pragma unroll
            for (int i = 0; i < 8; i += 2)
                *reinterpret_cast<short8*>(dst + i * 4) = pack8(s4[i], s4[i + 1]);
        }
        __syncthreads();
        #pragma unroll
        for (int kk = 0; kk < 64; kk += 32) {
            const int krd = kk + (lane >> 4) * 8;
            short8 af[4], bf_[4];
            #pragma unroll
            for (int i = 0; i < 4; i++)
                af[i] = *reinterpret_cast<const short8*>(&As[wm + i * 16 + (lane & 15)][krd]);
            #pragma unroll
            for (int i = 0; i < 4; i++)
                bf_[i] = *reinterpret_cast<const short8*>(&Bs[wn + i * 16 + (lane & 15)][krd]);
            #pragma unroll
            for (int i = 0; i < 4; i++)
                #pragma unroll
                for (int j = 0; j < 4; j++)
                    acc[i][j] = __builtin_amdgcn_mfma_f32_16x16x32_bf16(af[i], bf_[j], acc[i][j], 0, 0, 0);
        }
        __syncthreads();
    }

    const int ccol = lane & 15;
    const int crow = (lane >> 4) << 2;
    float bv[4];
    const float* bp = bias + branch * OUTF + n0 + wn;
    #pragma unroll
    for (int fn = 0; fn < 4; fn++) bv[fn] = bp[fn * 16 + ccol];
    #pragma unroll
    for (int fm = 0; fm < 4; fm++) {
        #pragma unroll
        for (int j = 0; j < 4; j++) {
            int gm = ltile * 128 + wm + fm * 16 + crow + j;
            if (gm < cnt) {
                int orow = rowlist[rbase + gm];
                float* orp = out + (size_t)orow * OUTF + n0 + wn;
                #pragma unroll
                for (int fn = 0; fn < 4; fn++)
                    orp[fn * 16 + ccol] = acc[fm][fn][j] + bv[fn];
            }
        }
    }
}

extern "C" void kernel_launch(void* const* d_in, const int* in_sizes, int n_in,
                              void* d_out, int out_size, void* d_ws, size_t ws_size,
                              hipStream_t stream) {
    const float* x = (const float*)d_in[0];
    const int* feat = (const int*)d_in[1];
    const float* w = (const float*)d_in[2];
    const float* bias = (const float*)d_in[3];
    float* out = (float*)d_out;

    char* ws = (char*)d_ws;
    int* ws_i = (int*)ws;
    int* rowlist = (int*)(ws + 256);                       // 266 KB
    const size_t WSW_OFF = (size_t)512 << 10;              // 512 KB
    unsigned short* wsw = (unsigned short*)(ws + WSW_OFF); // 8 MB bf16 W (pre-swizzled)
    const size_t need = WSW_OFF + (size_t)NBR * OUTF * OUTF * 2;  // ~8.9 MB

    (void)hipMemsetAsync(ws_i, 0, 64, stream);
    if (ws_size >= need)
        k_convw<<<2048, 256, 0, stream>>>(w, wsw);   // independent; overlaps count/fill
    k_count<<<NROWS / 256, 256, 0, stream>>>(feat, ws_i);
    k_fill<<<NROWS / 256, 256, 0, stream>>>(feat, ws_i, rowlist);

    if (ws_size >= need) {
        (void)hipFuncSetAttribute((const void*)k_gemm10,
                                  hipFuncAttributeMaxDynamicSharedMemorySize, 163840);
        k_gemm10<<<NWG, 512, 163840, stream>>>(x, wsw, bias, ws_i, rowlist, out);
    } else {
        dim3 grid(NROWS / 128 + NBR, OUTF / 128);
        k_gemm_fb<<<grid, 256, 0, stream>>>(x, w, bias, ws_i, rowlist, out);
    }
}